// Round 8
// baseline (22.832 us; speedup 1.0000x reference)
//
#include <hip/hip_runtime.h>
#include <math.h>

// Problem constants
#define B_  32
#define D_  64
#define L_  4096
#define E_  8
#define OC_ 32
#define LP_ 4094   // L - 2 (VALID conv, kernel 3)
#define TILE 64
#define NT   64    // tiles per batch (4096/64)

typedef __attribute__((ext_vector_type(8)))  short short8;
typedef __attribute__((ext_vector_type(16))) float float16;

static __device__ __forceinline__ unsigned short f2bf(float f) {
    unsigned u = __float_as_uint(f);
    return (unsigned short)((u + 0x7fffu + ((u >> 16) & 1u)) >> 16);
}
// packed f32x2 -> bf16x2 (low = a, high = b) in ONE instruction
static __device__ __forceinline__ unsigned cvtpk(float a, float b) {
    unsigned r;
    asm("v_cvt_pk_bf16_f32 %0, %1, %2" : "=v"(r) : "v"(a), "v"(b));
    return r;
}
// tanh via hw exp + rcp: 1 - 2/(e^{2x}+1)   (~5 VALU ops, err ~1e-5)
static __device__ __forceinline__ float fast_tanh(float x) {
    float e = __expf(2.0f * x);
    return fmaf(-2.0f, __builtin_amdgcn_rcpf(e + 1.0f), 1.0f);
}

// ---------------------------------------------------------------------------
// Workspace: beff f32[32][32] @0 (4KB) | aF bf16[12][64][8] @4096 (12KB)
//            wf2 bf16[B][2][64][8] @16384 (64KB)
// ---------------------------------------------------------------------------

// Prep: blocks 0..7 (wave w -> batch 4*blk+w): gates + Weff frags + beff.
//       block 8: conv1 A-fragments.
__global__ __launch_bounds__(256)
void prep_kernel(const float* __restrict__ x,
                 const float* __restrict__ w_gate,
                 const float* __restrict__ c1w,
                 const float* __restrict__ c2w,
                 const float* __restrict__ c2b,
                 float* __restrict__ beff,
                 unsigned short* __restrict__ aF,
                 unsigned short* __restrict__ wf2)
{
    const int tid = threadIdx.x;

    if (blockIdx.x == 8) {
        for (int i = tid; i < 12 * 64 * 8; i += 256) {
            int ks = i >> 9, lane = (i >> 3) & 63, ii = i & 7;
            int oc = lane & 31, half = lane >> 5;
            int kp = ks * 16 + half * 8 + ii;
            int t = kp >> 6, c = kp & 63;
            aF[i] = f2bf(c1w[oc * 192 + c * 3 + t]);
        }
        return;
    }

    const int wv = tid >> 6, lane = tid & 63;
    const int b  = blockIdx.x * 4 + wv;
    const int d  = lane;

    float xv[5];
    #pragma unroll
    for (int t = 0; t < 5; ++t)
        xv[t] = x[((size_t)b * D_ + d) * L_ + (L_ - 6) + t];

    float part[E_];
    #pragma unroll
    for (int e = 0; e < E_; ++e) part[e] = 0.f;
    #pragma unroll
    for (int t = 0; t < 5; ++t) {
        const float* wg = w_gate + (d * 5 + t) * E_;
        #pragma unroll
        for (int e = 0; e < E_; ++e) part[e] += xv[t] * wg[e];
    }
    #pragma unroll
    for (int off = 1; off < 64; off <<= 1) {
        #pragma unroll
        for (int e = 0; e < E_; ++e)
            part[e] += __shfl_xor(part[e], off, 64);
    }
    float m = part[0];
    #pragma unroll
    for (int e = 1; e < E_; ++e) m = fmaxf(m, part[e]);
    float p[E_], s = 0.f;
    #pragma unroll
    for (int e = 0; e < E_; ++e) { p[e] = expf(part[e] - m); s += p[e]; }
    float inv = 1.f / s;
    #pragma unroll
    for (int e = 0; e < E_; ++e) p[e] *= inv;

    int i0 = 0;
    #pragma unroll
    for (int e = 1; e < E_; ++e) if (p[e] > p[i0]) i0 = e;
    int i1 = (i0 == 0) ? 1 : 0;
    #pragma unroll
    for (int e = 0; e < E_; ++e) {
        if (e == i0) continue;
        if (p[e] > p[i1]) i1 = e;
    }
    const float v0 = p[i0], v1 = p[i1];
    const float den = v0 + v1 + 1e-6f;
    const float g0 = v0 / den, g1 = v1 / den;

    // Weff A-frags: A[m=dd=cl][k=oc], oc = ks*16 + (lane>>5)*8 + i
    {
        const int dd = lane & 31, half = lane >> 5;
        #pragma unroll
        for (int ks = 0; ks < 2; ++ks) {
            #pragma unroll
            for (int i = 0; i < 8; ++i) {
                int oc = ks * 16 + half * 8 + i;
                float v = g0 * c2w[(dd * E_ + i0) * OC_ + oc]
                        + g1 * c2w[(dd * E_ + i1) * OC_ + oc];
                wf2[((b * 2 + ks) * 64 + lane) * 8 + i] = f2bf(v);
            }
        }
    }
    if (d < OC_)
        beff[b * OC_ + d] = g0 * c2b[d * E_ + i0] + g1 * c2b[d * E_ + i1];
}

// ---------------------------------------------------------------------------
// Fused main v2: FINE-GRAINED blocks for phase staggering.
// Block = 128 threads (2 waves), TILE=64 cols, grid 2048 = 8 blocks/CU.
// 8 independent barrier domains per CU interleave staging (memory) and
// compute (MFMA/VALU) phases instead of marching in lockstep.
// LDS = xT only (8.4 KB); conv1 A-frags stream from L2-resident aF.
// ---------------------------------------------------------------------------
__global__ __launch_bounds__(128, 4)
void fused_main(const float* __restrict__ x,
                const unsigned short* __restrict__ aF,   // [12][64][8]
                const unsigned short* __restrict__ wf2,  // [B][2][64][8]
                const float* __restrict__ beff,          // [B][32]
                const float* __restrict__ c1b,           // [32]
                float* __restrict__ out)                 // [B][32][4094]
{
    // xT: bf16 [66 rows(l)][64 c] pitch 128 B, XOR-swizzle (row&7)<<4
    __shared__ __align__(16) unsigned short xT[66 * 64];   // 8448 B

    const int tid  = threadIdx.x;
    const int lane = tid & 63;
    const int wv   = tid >> 6;          // 0,1
    const int b    = blockIdx.x >> 6;
    const int l0   = (blockIdx.x & 63) << 6;
    const float* xb = x + (size_t)b * (D_ * L_);

    // ---- stage x tile: f32 [c][l] -> bf16 xT[l][c] (c-pairs packed) ----
    {
        const int c2 = tid >> 2;          // 0..31 channel pair
        const int j4 = (tid & 3) << 2;    // 0,4,8,12
        const float* p0 = xb + (size_t)(2 * c2) * L_ + l0;
        const float* p1 = p0 + L_;
        #pragma unroll
        for (int jq = 0; jq < 4; ++jq) {
            int j = jq * 16 + j4;
            float4 v0 = *(const float4*)(p0 + j);
            float4 v1 = *(const float4*)(p1 + j);
            float e0[4] = {v0.x, v0.y, v0.z, v0.w};
            float e1[4] = {v1.x, v1.y, v1.z, v1.w};
            #pragma unroll
            for (int r = 0; r < 4; ++r) {
                int row = j + r;
                int off = (row * 128 + c2 * 4) ^ ((row & 7) << 4);
                *(unsigned*)((char*)xT + off) = cvtpk(e0[r], e1[r]);
            }
        }
        if (tid < 64) {  // halo rows 64,65
            int cc2 = tid >> 1, jj = tid & 1;
            int row = TILE + jj;
            int lg  = l0 + row;
            float f0 = 0.f, f1 = 0.f;
            if (lg < L_) {
                f0 = xb[(size_t)(2 * cc2) * L_ + lg];
                f1 = xb[(size_t)(2 * cc2 + 1) * L_ + lg];
            }
            int off = (row * 128 + cc2 * 4) ^ ((row & 7) << 4);
            *(unsigned*)((char*)xT + off) = cvtpk(f0, f1);
        }
    }

    // ---- conv1 A-frags from L2-resident aF (issue before barrier so the
    //      ~300cyc L2 latency overlaps the barrier wait) ----
    short8 a1[12];
    #pragma unroll
    for (int ks = 0; ks < 12; ++ks)
        a1[ks] = *(const short8*)(aF + (ks * 64 + lane) * 8);

    const int cl = lane & 31;
    const int hi = lane >> 5;

    __syncthreads();

    // ---- conv1: 12 x mfma_32x32x16_bf16 ----
    const int cb = wv * 32;
    float16 acc = (float16)0.0f;
    #pragma unroll
    for (int t = 0; t < 3; ++t) {
        int row = cb + cl + t;
        int rb  = row * 128;
        int swz = (row & 7) << 4;
        #pragma unroll
        for (int q = 0; q < 4; ++q) {
            int off = (rb + q * 32 + hi * 16) ^ swz;
            short8 bf = *(const short8*)((const char*)xT + off);
            acc = __builtin_amdgcn_mfma_f32_32x32x16_bf16(a1[t * 4 + q], bf, acc, 0, 0, 0);
        }
    }

    // conv2 A-frags (deferred: keeps conv1-phase VGPR pressure low)
    short8 a2[2];
    a2[0] = *(const short8*)(wf2 + ((b * 2 + 0) * 64 + lane) * 8);
    a2[1] = *(const short8*)(wf2 + ((b * 2 + 1) * 64 + lane) * 8);

    // ---- bias + fast tanh ----
    float th[16];
    #pragma unroll
    for (int r = 0; r < 16; ++r) {
        int row = (r & 3) + 8 * (r >> 2) + 4 * hi;
        th[r] = fast_tanh(acc[r] + c1b[row]);
    }

    // ---- conv2 B-frags in-register via half-wave swap (lane ^ 32) ----
    unsigned x0a = hi ? cvtpk(th[0],  th[1])  : cvtpk(th[4],  th[5]);
    unsigned x0b = hi ? cvtpk(th[2],  th[3])  : cvtpk(th[6],  th[7]);
    unsigned x1a = hi ? cvtpk(th[8],  th[9])  : cvtpk(th[12], th[13]);
    unsigned x1b = hi ? cvtpk(th[10], th[11]) : cvtpk(th[14], th[15]);
    unsigned r0a = (unsigned)__shfl_xor((int)x0a, 32, 64);
    unsigned r0b = (unsigned)__shfl_xor((int)x0b, 32, 64);
    unsigned r1a = (unsigned)__shfl_xor((int)x1a, 32, 64);
    unsigned r1b = (unsigned)__shfl_xor((int)x1b, 32, 64);

    union U { short8 s8; unsigned u[4]; };
    U b0, b1;
    b0.u[0] = hi ? r0a : cvtpk(th[0], th[1]);
    b0.u[1] = hi ? r0b : cvtpk(th[2], th[3]);
    b0.u[2] = hi ? cvtpk(th[4], th[5]) : r0a;
    b0.u[3] = hi ? cvtpk(th[6], th[7]) : r0b;
    b1.u[0] = hi ? r1a : cvtpk(th[8], th[9]);
    b1.u[1] = hi ? r1b : cvtpk(th[10], th[11]);
    b1.u[2] = hi ? cvtpk(th[12], th[13]) : r1a;
    b1.u[3] = hi ? cvtpk(th[14], th[15]) : r1b;

    float16 acc2 = (float16)0.0f;
    acc2 = __builtin_amdgcn_mfma_f32_32x32x16_bf16(a2[0], b0.s8, acc2, 0, 0, 0);
    acc2 = __builtin_amdgcn_mfma_f32_32x32x16_bf16(a2[1], b1.s8, acc2, 0, 0, 0);

    // ---- direct stores (128B chunk per half-wave row) ----
    int l = l0 + cb + cl;
    if (l < LP_) {
        const float* be = beff + b * OC_;
        float* ob = out + (size_t)b * (OC_ * (size_t)LP_) + l;
        #pragma unroll
        for (int r = 0; r < 16; ++r) {
            int row = (r & 3) + 8 * (r >> 2) + 4 * hi;
            ob[(size_t)row * LP_] = acc2[r] + be[row];
        }
    }
}

// ---------------------------------------------------------------------------
extern "C" void kernel_launch(void* const* d_in, const int* in_sizes, int n_in,
                              void* d_out, int out_size, void* d_ws, size_t ws_size,
                              hipStream_t stream)
{
    const float* x      = (const float*)d_in[0];
    const float* w_gate = (const float*)d_in[1];
    const float* c1w    = (const float*)d_in[2];
    const float* c1b    = (const float*)d_in[3];
    const float* c2w    = (const float*)d_in[4];
    const float* c2b    = (const float*)d_in[5];
    float* out = (float*)d_out;

    char* ws = (char*)d_ws;
    float* beff         = (float*)ws;                    // 4096 B
    unsigned short* aF  = (unsigned short*)(ws + 4096);  // 12288 B
    unsigned short* wf2 = (unsigned short*)(ws + 16384); // 65536 B

    prep_kernel<<<9, 256, 0, stream>>>(x, w_gate, c1w, c2w, c2b, beff, aF, wf2);
    fused_main<<<B_ * NT, 128, 0, stream>>>(x, aF, wf2, beff, c1b, out);
}